// Round 7
// baseline (1525.802 us; speedup 1.0000x reference)
//
#include <hip/hip_runtime.h>
#include <hip/hip_fp16.h>
#include <math.h>

#define NN 100000
#define EE 3200000
#define ETOT (EE + NN)
#define NEG_SLOPE 0.2f
#define CHUNK 4096
#define NB0 ((ETOT + CHUNK - 1) / CHUNK)  // 806
#define RB 391                            // 256 * 391 >= NN
#define CAP 16384                         // window per coarse bucket
#define NCH 16                            // src chunks
#define SRCCH 6250                        // NN / NCH
#define BINS (RB * NCH)                   // 6256
#define AGRID 1024                        // persistent attn grid (4 blocks/CU)

typedef _Float16 half8 __attribute__((ext_vector_type(8)));
typedef _Float16 half4v __attribute__((ext_vector_type(4)));
typedef float floatx4 __attribute__((ext_vector_type(4)));

// ---------------- helpers ----------------
__device__ __forceinline__ float wsum64(float v) {
#pragma unroll
  for (int o = 32; o; o >>= 1) v += __shfl_xor(v, o);
  return v;
}
__device__ __forceinline__ float lrelu(float v) { return v > 0.f ? v : NEG_SLOPE * v; }
__device__ __forceinline__ float elu1(float v) { return v > 0.f ? v : expm1f(v); }

// ---------------- init: window cursors ----------------
__global__ void k_init(int* __restrict__ ccur) {
  ccur[threadIdx.x] = threadIdx.x * CAP;
}

// ---------------- pass1: bucketize edges into fixed windows + weight prep ----------------
// payload: (dloc:9 | src:17). No LDS staging: re-read ei (L2-warm) for placement.
__global__ __launch_bounds__(256) void k_pass1(const int* __restrict__ ei,
                                               int* __restrict__ ccur,
                                               unsigned* __restrict__ ebuf,
                                               const float* __restrict__ W1,
                                               const float* __restrict__ W2,
                                               _Float16* __restrict__ W1t,
                                               _Float16* __restrict__ W2t) {
  int b = blockIdx.x;
  if (b >= NB0) {  // weight prep blocks (192 x 256 = 49152 = 32768 + 16384)
    int idx = (b - NB0) * 256 + threadIdx.x;
    if (idx < 32768) {
      int n = idx >> 7, k = idx & 127;
      W1t[idx] = (_Float16)W1[k * 256 + n];
    } else {
      int j = idx - 32768;
      int n = j >> 8, k = j & 255;
      W2t[j] = (_Float16)W2[k * 64 + n];
    }
    return;
  }
  __shared__ int h[256];
  __shared__ int cur[256];
  int t = threadIdx.x;
  h[t] = 0;
  __syncthreads();
  int base = b * CHUNK;
  int lim = base + CHUNK; if (lim > ETOT) lim = ETOT;
  for (int e = base + t; e < lim; e += 256) {
    int d = (e < EE) ? ei[EE + e] : (e - EE);
    atomicAdd(&h[(unsigned)d / (unsigned)RB], 1);
  }
  __syncthreads();
  if (h[t]) cur[t] = atomicAdd(&ccur[t], h[t]);
  __syncthreads();
  for (int e = base + t; e < lim; e += 256) {
    int s, d;
    if (e < EE) { s = ei[e]; d = ei[EE + e]; } else { s = e - EE; d = s; }
    unsigned cb = (unsigned)d / (unsigned)RB;
    unsigned dloc = (unsigned)d - cb * (unsigned)RB;
    int pos = atomicAdd(&cur[cb], 1);
    ebuf[pos] = (dloc << 17) | (unsigned)s;
  }
}

// ---------------- pass2: chunk-sorted placement; emits offs/deg/choff/csr ----------------
// sort key within bucket: dloc*NCH + src_chunk
__global__ __launch_bounds__(256) void k_pass2(const unsigned* __restrict__ ebuf,
                                               const int* __restrict__ ccur,
                                               int* __restrict__ offs,
                                               int* __restrict__ degarr,
                                               int* __restrict__ csr,
                                               int* __restrict__ choff) {
  __shared__ int hist[BINS];
  __shared__ int psum[256];
  int b = blockIdx.x, t = threadIdx.x;
  int d0 = b * RB;
  int rb = NN - d0; if (rb > RB) rb = RB;
  int nbins = rb * NCH;
  int w0 = b * CAP;
  int cnt = ccur[b] - w0; if (cnt > CAP) cnt = CAP;
  for (int j = t; j < nbins; j += 256) hist[j] = 0;
  __syncthreads();
  for (int i = t; i < cnt; i += 256) {
    unsigned v = ebuf[w0 + i];
    unsigned bin = (v >> 17) * NCH + (v & 0x1FFFFu) / SRCCH;
    atomicAdd(&hist[bin], 1);
  }
  __syncthreads();
  const int PER = (BINS + 255) / 256;  // 25
  int lo = t * PER, hi = lo + PER;
  if (lo > nbins) lo = nbins;
  if (hi > nbins) hi = nbins;
  int s = 0;
  for (int j = lo; j < hi; ++j) s += hist[j];
  psum[t] = s;
  __syncthreads();
  for (int o = 1; o < 256; o <<= 1) {
    int add = (t >= o) ? psum[t - o] : 0;
    __syncthreads();
    psum[t] += add;
    __syncthreads();
  }
  int run = w0 + psum[t] - s;  // exclusive prefix, absolute
  for (int j = lo; j < hi; ++j) { int hv = hist[j]; hist[j] = run; run += hv; }
  __syncthreads();
  for (int j = t; j < rb; j += 256) {
    int st = hist[j * NCH];
    int en = (j == rb - 1) ? (w0 + cnt) : hist[(j + 1) * NCH];
    offs[d0 + j] = st;
    degarr[d0 + j] = en - st;
  }
  for (int j = t; j < nbins; j += 256) choff[(size_t)d0 * NCH + j] = hist[j];
  __syncthreads();
  for (int i = t; i < cnt; i += 256) {
    unsigned v = ebuf[w0 + i];
    unsigned s2 = v & 0x1FFFFu;
    unsigned bin = (v >> 17) * NCH + s2 / SRCCH;
    int pos = atomicAdd(&hist[bin], 1);
    csr[pos] = (int)s2;
  }
}

// ---------------- GEMM1 (MFMA fp16): h1h + as1/ad1 from x@W1, 2 heads/block ----------------
__global__ __launch_bounds__(256) void k_gemm1m(const float* __restrict__ x,
                                                const _Float16* __restrict__ W1t,
                                                const float* __restrict__ a_src,
                                                const float* __restrict__ a_dst,
                                                _Float16* __restrict__ h1h,
                                                float* __restrict__ as_out,
                                                float* __restrict__ ad_out) {
  __shared__ _Float16 As[64][136];
  __shared__ _Float16 Wt[128][136];
  const int bx = blockIdx.x & 1;
  const int by = blockIdx.x >> 1;
  const int tid = threadIdx.x;
  const int row0 = by * 64;
#pragma unroll
  for (int i = 0; i < 8; ++i) {
    int idx = i * 256 + tid;
    int r = idx >> 5;
    int c4 = (idx & 31) * 4;
    int gr = row0 + r;
    float4 f = make_float4(0.f, 0.f, 0.f, 0.f);
    if (gr < NN) f = *(const float4*)(x + (size_t)gr * 128 + c4);
    half4v h; h[0] = (_Float16)f.x; h[1] = (_Float16)f.y; h[2] = (_Float16)f.z; h[3] = (_Float16)f.w;
    *(half4v*)&As[r][c4] = h;
  }
#pragma unroll
  for (int i = 0; i < 8; ++i) {
    int idx = i * 256 + tid;
    int r = idx >> 4;
    int g = idx & 15;
    *(half8*)&Wt[r][g * 8] = *(const half8*)(W1t + (size_t)(bx * 128 + r) * 128 + g * 8);
  }
  __syncthreads();

  const int wid = tid >> 6, lane = tid & 63;
  const int m16 = lane & 15, quad = lane >> 4;
  floatx4 acc[8];
#pragma unroll
  for (int nt = 0; nt < 8; ++nt) acc[nt] = (floatx4){0.f, 0.f, 0.f, 0.f};
#pragma unroll
  for (int ks = 0; ks < 4; ++ks) {
    half8 av = *(half8*)&As[wid * 16 + m16][ks * 32 + quad * 8];
#pragma unroll
    for (int nt = 0; nt < 8; ++nt) {
      half8 bv = *(half8*)&Wt[nt * 16 + m16][ks * 32 + quad * 8];
      acc[nt] = __builtin_amdgcn_mfma_f32_16x16x32_f16(av, bv, acc[nt], 0, 0, 0);
    }
  }
  float asr[8], adr[8];
#pragma unroll
  for (int nt = 0; nt < 8; ++nt) {
    asr[nt] = a_src[bx * 128 + nt * 16 + m16];
    adr[nt] = a_dst[bx * 128 + nt * 16 + m16];
  }
#pragma unroll
  for (int r = 0; r < 4; ++r) {
    int gr = row0 + wid * 16 + quad * 4 + r;
    bool ok = gr < NN;
#pragma unroll
    for (int hp = 0; hp < 2; ++hp) {
      float ps = 0.f, pd = 0.f;
#pragma unroll
      for (int j = 0; j < 4; ++j) {
        ps = fmaf(acc[hp * 4 + j][r], asr[hp * 4 + j], ps);
        pd = fmaf(acc[hp * 4 + j][r], adr[hp * 4 + j], pd);
      }
#pragma unroll
      for (int o = 1; o < 16; o <<= 1) { ps += __shfl_xor(ps, o); pd += __shfl_xor(pd, o); }
      if (ok && m16 == 0) {
        as_out[gr * 4 + bx * 2 + hp] = ps;
        ad_out[gr * 4 + bx * 2 + hp] = pd;
      }
    }
    if (ok) {
#pragma unroll
      for (int nt = 0; nt < 8; ++nt)
        h1h[(size_t)gr * 256 + bx * 128 + nt * 16 + m16] = (_Float16)acc[nt][r];
    }
  }
}

// ---------------- GEMM2 (MFMA fp16): h2h + as2/ad2 from h1e@W2 ----------------
__global__ __launch_bounds__(256) void k_gemm2m(const _Float16* __restrict__ h1e,
                                                const _Float16* __restrict__ W2t,
                                                const float* __restrict__ a_src,
                                                const float* __restrict__ a_dst,
                                                _Float16* __restrict__ h2h,
                                                float* __restrict__ as_out,
                                                float* __restrict__ ad_out) {
  __shared__ _Float16 As2[64][136];
  __shared__ _Float16 Wt2[64][264];
  const int by = blockIdx.x;
  const int tid = threadIdx.x;
  const int row0 = by * 64;
#pragma unroll
  for (int i = 0; i < 8; ++i) {
    int idx = i * 256 + tid;
    int r = idx >> 5;
    int g = idx & 31;
    *(half8*)&Wt2[r][g * 8] = *(const half8*)(W2t + (size_t)r * 256 + g * 8);
  }
  const int wid = tid >> 6, lane = tid & 63;
  const int m16 = lane & 15, quad = lane >> 4;
  floatx4 acc[4];
#pragma unroll
  for (int nt = 0; nt < 4; ++nt) acc[nt] = (floatx4){0.f, 0.f, 0.f, 0.f};

  for (int kc = 0; kc < 2; ++kc) {
#pragma unroll
    for (int i = 0; i < 4; ++i) {
      int idx = i * 256 + tid;
      int r = idx >> 4;
      int g = idx & 15;
      int gr = row0 + r;
      half8 v = {0, 0, 0, 0, 0, 0, 0, 0};
      if (gr < NN) v = *(const half8*)(h1e + (size_t)gr * 256 + kc * 128 + g * 8);
      *(half8*)&As2[r][g * 8] = v;
    }
    __syncthreads();
#pragma unroll
    for (int ks = 0; ks < 4; ++ks) {
      half8 av = *(half8*)&As2[wid * 16 + m16][ks * 32 + quad * 8];
#pragma unroll
      for (int nt = 0; nt < 4; ++nt) {
        half8 bv = *(half8*)&Wt2[nt * 16 + m16][kc * 128 + ks * 32 + quad * 8];
        acc[nt] = __builtin_amdgcn_mfma_f32_16x16x32_f16(av, bv, acc[nt], 0, 0, 0);
      }
    }
    __syncthreads();
  }
  float asr[4], adr[4];
#pragma unroll
  for (int nt = 0; nt < 4; ++nt) {
    asr[nt] = a_src[nt * 16 + m16];
    adr[nt] = a_dst[nt * 16 + m16];
  }
#pragma unroll
  for (int r = 0; r < 4; ++r) {
    float ps = 0.f, pd = 0.f;
#pragma unroll
    for (int nt = 0; nt < 4; ++nt) {
      ps = fmaf(acc[nt][r], asr[nt], ps);
      pd = fmaf(acc[nt][r], adr[nt], pd);
    }
#pragma unroll
    for (int o = 1; o < 16; o <<= 1) { ps += __shfl_xor(ps, o); pd += __shfl_xor(pd, o); }
    int gr = row0 + wid * 16 + quad * 4 + r;
    if (gr < NN) {
      if (m16 == 0) { as_out[gr] = ps; ad_out[gr] = pd; }
#pragma unroll
      for (int nt = 0; nt < 4; ++nt)
        h2h[(size_t)gr * 64 + nt * 16 + m16] = (_Float16)acc[nt][r];
    }
  }
}

// ---------------- attn1: persistent chunk-swept, 8 dsts/wave, weights recomputed ----
__global__ __launch_bounds__(256, 4) void k_attn1(const int* __restrict__ offs,
                                                  const int* __restrict__ degarr,
                                                  const int* __restrict__ csr,
                                                  const int* __restrict__ choff,
                                                  const float* __restrict__ a_s,
                                                  const float* __restrict__ a_d,
                                                  const _Float16* __restrict__ h1h,
                                                  const float* __restrict__ b1,
                                                  _Float16* __restrict__ h1e) {
  const int wid = threadIdx.x >> 6, lane = threadIdx.x & 63;
  const int h = lane >> 4;
  const int slot = blockIdx.x * 4 + wid;       // 0..4095
  const int c0 = lane * 4;
  const float4 bb = *(const float4*)(b1 + c0);
  for (int base = slot * 8; base < NN; base += AGRID * 32) {
    float inv[8], adh[8];
    int dbeg[8], ddeg[8];
    float4 acc[8];
#pragma unroll
    for (int d = 0; d < 8; ++d) {
      acc[d] = make_float4(0.f, 0.f, 0.f, 0.f);
      ddeg[d] = 0;
      int n = base + d;
      if (n < NN) {
        int beg = offs[n], dg = degarr[n];
        dbeg[d] = beg; ddeg[d] = dg;
        float4 ad = *(const float4*)(a_d + (size_t)n * 4);
        adh[d] = (h & 2) ? ((h & 1) ? ad.w : ad.z) : ((h & 1) ? ad.y : ad.x);
        float4 sm = make_float4(0.f, 0.f, 0.f, 0.f);
        for (int e = lane; e < dg; e += 64) {
          int s = csr[beg + e];
          float4 as = *(const float4*)(a_s + (size_t)s * 4);
          sm.x += __expf(lrelu(as.x + ad.x));
          sm.y += __expf(lrelu(as.y + ad.y));
          sm.z += __expf(lrelu(as.z + ad.z));
          sm.w += __expf(lrelu(as.w + ad.w));
        }
        sm.x = wsum64(sm.x); sm.y = wsum64(sm.y); sm.z = wsum64(sm.z); sm.w = wsum64(sm.w);
        float dh = (h & 2) ? ((h & 1) ? sm.w : sm.z) : ((h & 1) ? sm.y : sm.x);
        inv[d] = 1.f / dh;
      }
    }
    for (int c = 0; c < NCH; ++c) {
#pragma unroll
      for (int d = 0; d < 8; ++d) {
        if (ddeg[d] == 0) continue;
        int n = base + d;
        int jb = choff[(size_t)n * NCH + c];
        int je = (c == NCH - 1) ? (dbeg[d] + ddeg[d]) : choff[(size_t)n * NCH + c + 1];
        int j = jb;
        for (; j + 2 <= je; j += 2) {
          int s0 = csr[j], s1 = csr[j + 1];
          float w0 = __expf(lrelu(a_s[(size_t)s0 * 4 + h] + adh[d])) * inv[d];
          float w1 = __expf(lrelu(a_s[(size_t)s1 * 4 + h] + adh[d])) * inv[d];
          half4v r0 = *(const half4v*)(h1h + (size_t)s0 * 256 + c0);
          half4v r1 = *(const half4v*)(h1h + (size_t)s1 * 256 + c0);
          acc[d].x = fmaf((float)r0[0], w0, acc[d].x);
          acc[d].y = fmaf((float)r0[1], w0, acc[d].y);
          acc[d].z = fmaf((float)r0[2], w0, acc[d].z);
          acc[d].w = fmaf((float)r0[3], w0, acc[d].w);
          acc[d].x = fmaf((float)r1[0], w1, acc[d].x);
          acc[d].y = fmaf((float)r1[1], w1, acc[d].y);
          acc[d].z = fmaf((float)r1[2], w1, acc[d].z);
          acc[d].w = fmaf((float)r1[3], w1, acc[d].w);
        }
        if (j < je) {
          int s0 = csr[j];
          float w0 = __expf(lrelu(a_s[(size_t)s0 * 4 + h] + adh[d])) * inv[d];
          half4v r0 = *(const half4v*)(h1h + (size_t)s0 * 256 + c0);
          acc[d].x = fmaf((float)r0[0], w0, acc[d].x);
          acc[d].y = fmaf((float)r0[1], w0, acc[d].y);
          acc[d].z = fmaf((float)r0[2], w0, acc[d].z);
          acc[d].w = fmaf((float)r0[3], w0, acc[d].w);
        }
      }
    }
#pragma unroll
    for (int d = 0; d < 8; ++d) {
      int n = base + d;
      if (n < NN) {
        half4v o;
        o[0] = (_Float16)elu1(acc[d].x + bb.x);
        o[1] = (_Float16)elu1(acc[d].y + bb.y);
        o[2] = (_Float16)elu1(acc[d].z + bb.z);
        o[3] = (_Float16)elu1(acc[d].w + bb.w);
        *(half4v*)(h1e + (size_t)n * 256 + c0) = o;
      }
    }
  }
}

// ---------------- attn2: persistent chunk-swept + final linear ----------------
__global__ __launch_bounds__(256, 4) void k_attn2(const int* __restrict__ offs,
                                                  const int* __restrict__ degarr,
                                                  const int* __restrict__ csr,
                                                  const int* __restrict__ choff,
                                                  const float* __restrict__ a_s,
                                                  const float* __restrict__ a_d,
                                                  const _Float16* __restrict__ h2h,
                                                  const float* __restrict__ b2,
                                                  const float* __restrict__ lin_w,
                                                  const float* __restrict__ lin_b,
                                                  float* __restrict__ out) {
  const int wid = threadIdx.x >> 6, lane = threadIdx.x & 63;
  const int slot = blockIdx.x * 4 + wid;
  const float b2l = b2[lane];
  const float lw0 = lin_w[lane * 2 + 0];
  const float lw1 = lin_w[lane * 2 + 1];
  const float lb0 = lin_b[0], lb1 = lin_b[1];
  for (int base = slot * 8; base < NN; base += AGRID * 32) {
    float inv[8], adn[8];
    int dbeg[8], ddeg[8];
    float acc[8];
#pragma unroll
    for (int d = 0; d < 8; ++d) {
      acc[d] = 0.f;
      ddeg[d] = 0;
      int n = base + d;
      if (n < NN) {
        int beg = offs[n], dg = degarr[n];
        dbeg[d] = beg; ddeg[d] = dg;
        float ad = a_d[n];
        adn[d] = ad;
        float sm = 0.f;
        for (int e = lane; e < dg; e += 64) {
          int s = csr[beg + e];
          sm += __expf(lrelu(a_s[s] + ad));
        }
        sm = wsum64(sm);
        inv[d] = 1.f / sm;
      }
    }
    for (int c = 0; c < NCH; ++c) {
#pragma unroll
      for (int d = 0; d < 8; ++d) {
        if (ddeg[d] == 0) continue;
        int n = base + d;
        int jb = choff[(size_t)n * NCH + c];
        int je = (c == NCH - 1) ? (dbeg[d] + ddeg[d]) : choff[(size_t)n * NCH + c + 1];
        int j = jb;
        for (; j + 2 <= je; j += 2) {
          int s0 = csr[j], s1 = csr[j + 1];
          float w0 = __expf(lrelu(a_s[s0] + adn[d])) * inv[d];
          float w1 = __expf(lrelu(a_s[s1] + adn[d])) * inv[d];
          float v0 = (float)h2h[(size_t)s0 * 64 + lane];
          float v1 = (float)h2h[(size_t)s1 * 64 + lane];
          acc[d] = fmaf(v0, w0, acc[d]);
          acc[d] = fmaf(v1, w1, acc[d]);
        }
        if (j < je) {
          int s0 = csr[j];
          float w0 = __expf(lrelu(a_s[s0] + adn[d])) * inv[d];
          acc[d] = fmaf((float)h2h[(size_t)s0 * 64 + lane], w0, acc[d]);
        }
      }
    }
#pragma unroll
    for (int d = 0; d < 8; ++d) {
      int n = base + d;
      if (n < NN) {
        float o = elu1(acc[d] + b2l);
        float p0 = wsum64(o * lw0);
        float p1 = wsum64(o * lw1);
        if (lane == 0) {
          out[n * 2 + 0] = p0 + lb0;
          out[n * 2 + 1] = p1 + lb1;
        }
      }
    }
  }
}

// ---------------- launch ----------------
extern "C" void kernel_launch(void* const* d_in, const int* in_sizes, int n_in,
                              void* d_out, int out_size, void* d_ws, size_t ws_size,
                              hipStream_t stream) {
  const float* x      = (const float*)d_in[0];
  const int*   ei     = (const int*)d_in[1];
  const float* W1     = (const float*)d_in[2];
  const float* a_src1 = (const float*)d_in[3];
  const float* a_dst1 = (const float*)d_in[4];
  const float* b1     = (const float*)d_in[5];
  const float* W2     = (const float*)d_in[6];
  const float* a_src2 = (const float*)d_in[7];
  const float* a_dst2 = (const float*)d_in[8];
  const float* b2     = (const float*)d_in[9];
  const float* lin_w  = (const float*)d_in[10];
  const float* lin_b  = (const float*)d_in[11];
  float* outp = (float*)d_out;

  char* w = (char*)d_ws;
  _Float16* h1h = (_Float16*)(w + 0);            // 51,200,000
  _Float16* h1e = (_Float16*)(w + 51200000);     // 51,200,000
  _Float16* h2h = (_Float16*)(w + 102400000);    // 12,800,000
  _Float16* W1t = (_Float16*)(w + 115200000);    // 65,536
  _Float16* W2t = (_Float16*)(w + 115265536);    // 32,768
  float*  as1 = (float*)(w + 115298304);         // 1,600,000
  float*  ad1 = (float*)(w + 116898304);         // 1,600,000
  float*  as2 = (float*)(w + 118498304);         // 400,000
  float*  ad2 = (float*)(w + 118898304);         // 400,000
  int*    offs = (int*)(w + 119298304);          // 400,000
  int*    degarr = (int*)(w + 119698304);        // 400,000
  int*    ccur = (int*)(w + 120098304);          // 1,024
  unsigned* ebuf = (unsigned*)(w + 120099328);   // 16,777,216
  int*    csr = (int*)(w + 136876544);           // 16,777,216
  int*    choff = (int*)(w + 153653760);         // 6,400,000

  // CSR build (fixed-window counting sort, chunk-sorted) + weight prep
  k_init<<<1, 256, 0, stream>>>(ccur);
  k_pass1<<<NB0 + 192, 256, 0, stream>>>(ei, ccur, ebuf, W1, W2, W1t, W2t);
  k_pass2<<<256, 256, 0, stream>>>(ebuf, ccur, offs, degarr, csr, choff);

  // layer 1
  k_gemm1m<<<2 * 1563, 256, 0, stream>>>(x, W1t, a_src1, a_dst1, h1h, as1, ad1);
  k_attn1<<<AGRID, 256, 0, stream>>>(offs, degarr, csr, choff, as1, ad1, h1h, b1, h1e);

  // layer 2
  k_gemm2m<<<1563, 256, 0, stream>>>(h1e, W2t, a_src2, a_dst2, h2h, as2, ad2);
  k_attn2<<<AGRID, 256, 0, stream>>>(offs, degarr, csr, choff, as2, ad2, h2h, b2, lin_w, lin_b, outp);
}

// Round 8
// 637.789 us; speedup vs baseline: 2.3923x; 2.3923x over previous
//
#include <hip/hip_runtime.h>
#include <hip/hip_fp16.h>
#include <math.h>

#define NN 100000
#define EE 3200000
#define ETOT (EE + NN)
#define NEG_SLOPE 0.2f
#define DMAX 96
#define CHUNK 4096
#define NB0 ((ETOT + CHUNK - 1) / CHUNK)  // 806
#define RB 391                            // 256 * 391 >= NN
#define CAP 16384                         // window per coarse bucket
#define G1B 3126                          // gemm1 blocks: 2 * ceil(NN/64)

typedef _Float16 half8 __attribute__((ext_vector_type(8)));
typedef _Float16 half4v __attribute__((ext_vector_type(4)));
typedef float floatx4 __attribute__((ext_vector_type(4)));

// ---------------- helpers ----------------
__device__ __forceinline__ float wsum64(float v) {
#pragma unroll
  for (int o = 32; o; o >>= 1) v += __shfl_xor(v, o);
  return v;
}
__device__ __forceinline__ float lrelu(float v) { return v > 0.f ? v : NEG_SLOPE * v; }
__device__ __forceinline__ float elu1(float v) { return v > 0.f ? v : expm1f(v); }

// ---------------- fused1: pass1 (bucketize) + gemm1 (x@W1 -> h1h, as1, ad1) ----------------
// blocks [0, NB0): edge bucketize into fixed windows; ccur holds per-bucket COUNTS.
// blocks [NB0, NB0+G1B): MFMA gemm1, 2 heads (128 cols) per block, W1 transposed from global.
__global__ __launch_bounds__(256) void k_fused1(const int* __restrict__ ei,
                                                int* __restrict__ ccur,
                                                unsigned* __restrict__ ebuf,
                                                const float* __restrict__ x,
                                                const float* __restrict__ W1,
                                                const float* __restrict__ a_src,
                                                const float* __restrict__ a_dst,
                                                _Float16* __restrict__ h1h,
                                                float* __restrict__ as_out,
                                                float* __restrict__ ad_out) {
  __shared__ __align__(16) char smem[52224];  // union: pass1 (2 KB) / gemm1 (51 KB)
  const int b = blockIdx.x;
  const int t = threadIdx.x;
  if (b < NB0) {  // ---- pass1 ----
    int* h = (int*)smem;
    int* cur = (int*)(smem + 1024);
    h[t] = 0;
    __syncthreads();
    int base = b * CHUNK;
    int lim = base + CHUNK; if (lim > ETOT) lim = ETOT;
    for (int e = base + t; e < lim; e += 256) {
      int d = (e < EE) ? ei[EE + e] : (e - EE);
      atomicAdd(&h[(unsigned)d / (unsigned)RB], 1);
    }
    __syncthreads();
    if (h[t]) cur[t] = t * CAP + atomicAdd(&ccur[t], h[t]);
    __syncthreads();
    for (int e = base + t; e < lim; e += 256) {
      int s, d;
      if (e < EE) { s = ei[e]; d = ei[EE + e]; } else { s = e - EE; d = s; }
      unsigned cb = (unsigned)d / (unsigned)RB;
      unsigned dloc = (unsigned)d - cb * (unsigned)RB;
      int pos = atomicAdd(&cur[cb], 1);
      ebuf[pos] = (dloc << 17) | (unsigned)s;
    }
    return;
  }
  // ---- gemm1 ----
  _Float16 (*As)[136] = (_Float16(*)[136])smem;             // 64 x 136 = 17408 B
  _Float16 (*Wt)[136] = (_Float16(*)[136])(smem + 17408);   // 128 x 136 = 34816 B
  const int bb = b - NB0;
  const int bx = bb & 1;
  const int by = bb >> 1;
  const int row0 = by * 64;
  // stage A (fp32 -> fp16): 64 x 128
#pragma unroll
  for (int i = 0; i < 8; ++i) {
    int idx = i * 256 + t;
    int r = idx >> 5;
    int c4 = (idx & 31) * 4;
    int gr = row0 + r;
    float4 f = make_float4(0.f, 0.f, 0.f, 0.f);
    if (gr < NN) f = *(const float4*)(x + (size_t)gr * 128 + c4);
    half4v hv; hv[0] = (_Float16)f.x; hv[1] = (_Float16)f.y; hv[2] = (_Float16)f.z; hv[3] = (_Float16)f.w;
    *(half4v*)&As[r][c4] = hv;
  }
  // transpose-stage W1 -> Wt: Wt[n][k] = W1[k][bx*128 + n], n in [0,128)
#pragma unroll
  for (int i = 0; i < 16; ++i) {
    int idx = i * 256 + t;          // 0..4095
    int k = idx >> 5;               // 0..127
    int n4 = (idx & 31) * 4;        // 0..124
    float4 f = *(const float4*)(W1 + (size_t)k * 256 + bx * 128 + n4);
    Wt[n4 + 0][k] = (_Float16)f.x;
    Wt[n4 + 1][k] = (_Float16)f.y;
    Wt[n4 + 2][k] = (_Float16)f.z;
    Wt[n4 + 3][k] = (_Float16)f.w;
  }
  __syncthreads();

  const int wid = t >> 6, lane = t & 63;
  const int m16 = lane & 15, quad = lane >> 4;
  floatx4 acc[8];
#pragma unroll
  for (int nt = 0; nt < 8; ++nt) acc[nt] = (floatx4){0.f, 0.f, 0.f, 0.f};
#pragma unroll
  for (int ks = 0; ks < 4; ++ks) {
    half8 av = *(half8*)&As[wid * 16 + m16][ks * 32 + quad * 8];
#pragma unroll
    for (int nt = 0; nt < 8; ++nt) {
      half8 bv = *(half8*)&Wt[nt * 16 + m16][ks * 32 + quad * 8];
      acc[nt] = __builtin_amdgcn_mfma_f32_16x16x32_f16(av, bv, acc[nt], 0, 0, 0);
    }
  }
  float asr[8], adr[8];
#pragma unroll
  for (int nt = 0; nt < 8; ++nt) {
    asr[nt] = a_src[bx * 128 + nt * 16 + m16];
    adr[nt] = a_dst[bx * 128 + nt * 16 + m16];
  }
#pragma unroll
  for (int r = 0; r < 4; ++r) {
    int gr = row0 + wid * 16 + quad * 4 + r;
    bool ok = gr < NN;
#pragma unroll
    for (int hp = 0; hp < 2; ++hp) {
      float ps = 0.f, pd = 0.f;
#pragma unroll
      for (int j = 0; j < 4; ++j) {
        ps = fmaf(acc[hp * 4 + j][r], asr[hp * 4 + j], ps);
        pd = fmaf(acc[hp * 4 + j][r], adr[hp * 4 + j], pd);
      }
#pragma unroll
      for (int o = 1; o < 16; o <<= 1) { ps += __shfl_xor(ps, o); pd += __shfl_xor(pd, o); }
      if (ok && m16 == 0) {
        as_out[gr * 4 + bx * 2 + hp] = ps;
        ad_out[gr * 4 + bx * 2 + hp] = pd;
      }
    }
    if (ok) {
#pragma unroll
      for (int nt = 0; nt < 8; ++nt)
        h1h[(size_t)gr * 256 + bx * 128 + nt * 16 + m16] = (_Float16)acc[nt][r];
    }
  }
}

// ---------------- pass2: per-bucket exact placement via LDS cursors; emits offs+deg+csr ----
__global__ __launch_bounds__(256) void k_pass2(const unsigned* __restrict__ ebuf,
                                               const int* __restrict__ ccur,
                                               int* __restrict__ offs,
                                               int* __restrict__ degarr,
                                               int* __restrict__ csr) {
  __shared__ unsigned ed[CAP];
  __shared__ int hist[RB];
  __shared__ int cur[RB];
  int b = blockIdx.x, t = threadIdx.x;
  int d0 = b * RB;
  int rb = NN - d0; if (rb > RB) rb = RB;
  int w0 = b * CAP;
  int cnt = ccur[b];
  if (cnt > CAP) cnt = CAP;  // statistical impossibility guard
  for (int j = t; j < rb; j += 256) hist[j] = 0;
  __syncthreads();
  for (int i = t; i < cnt; i += 256) {
    unsigned v = ebuf[w0 + i];
    ed[i] = v;
    atomicAdd(&hist[v >> 17], 1);
  }
  __syncthreads();
  if (t == 0) {
    int run = w0;
    for (int j = 0; j < rb; ++j) { cur[j] = run; run += hist[j]; }
  }
  __syncthreads();
  for (int j = t; j < rb; j += 256) {
    offs[d0 + j] = cur[j];
    degarr[d0 + j] = hist[j];
  }
  __syncthreads();
  for (int i = t; i < cnt; i += 256) {
    unsigned v = ed[i];
    int pos = atomicAdd(&cur[v >> 17], 1);
    csr[pos] = (int)(v & 0x1FFFFu);
  }
}

// ---------------- GEMM2 (MFMA fp16): h2h + as2/ad2 from h1e@W2, W2 transposed from global ----
__global__ __launch_bounds__(256) void k_gemm2m(const _Float16* __restrict__ h1e,
                                                const float* __restrict__ W2,
                                                const float* __restrict__ a_src,
                                                const float* __restrict__ a_dst,
                                                _Float16* __restrict__ h2h,
                                                float* __restrict__ as_out,
                                                float* __restrict__ ad_out) {
  __shared__ _Float16 As2[64][136];
  __shared__ _Float16 Wt2[64][264];
  const int by = blockIdx.x;
  const int tid = threadIdx.x;
  const int row0 = by * 64;
  // transpose-stage W2 -> Wt2: Wt2[n][k] = W2[k][n]
#pragma unroll
  for (int i = 0; i < 16; ++i) {
    int idx = i * 256 + tid;        // 0..4095
    int k = idx >> 4;               // 0..255
    int n4 = (idx & 15) * 4;        // 0..60
    float4 f = *(const float4*)(W2 + (size_t)k * 64 + n4);
    Wt2[n4 + 0][k] = (_Float16)f.x;
    Wt2[n4 + 1][k] = (_Float16)f.y;
    Wt2[n4 + 2][k] = (_Float16)f.z;
    Wt2[n4 + 3][k] = (_Float16)f.w;
  }
  const int wid = tid >> 6, lane = tid & 63;
  const int m16 = lane & 15, quad = lane >> 4;
  floatx4 acc[4];
#pragma unroll
  for (int nt = 0; nt < 4; ++nt) acc[nt] = (floatx4){0.f, 0.f, 0.f, 0.f};

  for (int kc = 0; kc < 2; ++kc) {
#pragma unroll
    for (int i = 0; i < 4; ++i) {
      int idx = i * 256 + tid;
      int r = idx >> 4;
      int g = idx & 15;
      int gr = row0 + r;
      half8 v = {0, 0, 0, 0, 0, 0, 0, 0};
      if (gr < NN) v = *(const half8*)(h1e + (size_t)gr * 256 + kc * 128 + g * 8);
      *(half8*)&As2[r][g * 8] = v;
    }
    __syncthreads();
#pragma unroll
    for (int ks = 0; ks < 4; ++ks) {
      half8 av = *(half8*)&As2[wid * 16 + m16][ks * 32 + quad * 8];
#pragma unroll
      for (int nt = 0; nt < 4; ++nt) {
        half8 bv = *(half8*)&Wt2[nt * 16 + m16][kc * 128 + ks * 32 + quad * 8];
        acc[nt] = __builtin_amdgcn_mfma_f32_16x16x32_f16(av, bv, acc[nt], 0, 0, 0);
      }
    }
    __syncthreads();
  }
  float asr[4], adr[4];
#pragma unroll
  for (int nt = 0; nt < 4; ++nt) {
    asr[nt] = a_src[nt * 16 + m16];
    adr[nt] = a_dst[nt * 16 + m16];
  }
#pragma unroll
  for (int r = 0; r < 4; ++r) {
    float ps = 0.f, pd = 0.f;
#pragma unroll
    for (int nt = 0; nt < 4; ++nt) {
      ps = fmaf(acc[nt][r], asr[nt], ps);
      pd = fmaf(acc[nt][r], adr[nt], pd);
    }
#pragma unroll
    for (int o = 1; o < 16; o <<= 1) { ps += __shfl_xor(ps, o); pd += __shfl_xor(pd, o); }
    int gr = row0 + wid * 16 + quad * 4 + r;
    if (gr < NN) {
      if (m16 == 0) { as_out[gr] = ps; ad_out[gr] = pd; }
#pragma unroll
      for (int nt = 0; nt < 4; ++nt)
        h2h[(size_t)gr * 64 + nt * 16 + m16] = (_Float16)acc[nt][r];
    }
  }
}

// ---------------- fused attention layer 1 -> h1e (fp16) ----------------
// one wave per dst node; phase 2: full wave, 8 B/lane, 8-unroll (round-6 proven shape).
__global__ __launch_bounds__(256) void k_attn1(const int* __restrict__ offs,
                                               const int* __restrict__ degarr,
                                               const int* __restrict__ csr_src,
                                               const float* __restrict__ a_s,
                                               const float* __restrict__ a_d,
                                               const _Float16* __restrict__ h1h,
                                               const float* __restrict__ b1,
                                               _Float16* __restrict__ h1e) {
  __shared__ float alpha[4][DMAX][4];
  __shared__ int sidx[4][DMAX];
  const int wid = threadIdx.x >> 6;
  const int n = blockIdx.x * 4 + wid;
  const int lane = threadIdx.x & 63;
  const int beg = offs[n], deg = degarr[n];
  const float4 ad = *(const float4*)(a_d + n * 4);
  float4 sm = make_float4(0.f, 0.f, 0.f, 0.f);
  for (int d = lane; d < deg; d += 64) {
    int s = __builtin_nontemporal_load(csr_src + beg + d);
    float4 as = *(const float4*)(a_s + s * 4);
    float e0 = __expf(lrelu(as.x + ad.x));
    float e1 = __expf(lrelu(as.y + ad.y));
    float e2 = __expf(lrelu(as.z + ad.z));
    float e3 = __expf(lrelu(as.w + ad.w));
    sm.x += e0; sm.y += e1; sm.z += e2; sm.w += e3;
    if (d < DMAX) {
      sidx[wid][d] = s;
      *(float4*)&alpha[wid][d][0] = make_float4(e0, e1, e2, e3);
    }
  }
  sm.x = wsum64(sm.x); sm.y = wsum64(sm.y); sm.z = wsum64(sm.z); sm.w = wsum64(sm.w);
  const float4 inv4 = make_float4(1.f / sm.x, 1.f / sm.y, 1.f / sm.z, 1.f / sm.w);
  const int dlim = deg < DMAX ? deg : DMAX;
  for (int d = lane; d < dlim; d += 64) {
    float4 a = *(float4*)&alpha[wid][d][0];
    a.x *= inv4.x; a.y *= inv4.y; a.z *= inv4.z; a.w *= inv4.w;
    *(float4*)&alpha[wid][d][0] = a;
  }
  const int h = lane >> 4;
  float4 acc = make_float4(0.f, 0.f, 0.f, 0.f);
  int d = 0;
  for (; d + 8 <= dlim; d += 8) {
    int ss[8]; float ww[8];
#pragma unroll
    for (int u = 0; u < 8; ++u) {
      ss[u] = sidx[wid][d + u];
      ww[u] = alpha[wid][d + u][h];
    }
    half4v rr[8];
#pragma unroll
    for (int u = 0; u < 8; ++u)
      rr[u] = *(const half4v*)(h1h + (size_t)ss[u] * 256 + lane * 4);
#pragma unroll
    for (int u = 0; u < 8; ++u) {
      acc.x = fmaf((float)rr[u][0], ww[u], acc.x);
      acc.y = fmaf((float)rr[u][1], ww[u], acc.y);
      acc.z = fmaf((float)rr[u][2], ww[u], acc.z);
      acc.w = fmaf((float)rr[u][3], ww[u], acc.w);
    }
  }
  for (; d < dlim; ++d) {
    int s = sidx[wid][d];
    float w = alpha[wid][d][h];
    half4v r = *(const half4v*)(h1h + (size_t)s * 256 + lane * 4);
    acc.x = fmaf((float)r[0], w, acc.x); acc.y = fmaf((float)r[1], w, acc.y);
    acc.z = fmaf((float)r[2], w, acc.z); acc.w = fmaf((float)r[3], w, acc.w);
  }
  const float adh = (h & 2) ? ((h & 1) ? ad.w : ad.z) : ((h & 1) ? ad.y : ad.x);
  const float invh = (h & 2) ? ((h & 1) ? inv4.w : inv4.z) : ((h & 1) ? inv4.y : inv4.x);
  for (; d < deg; ++d) {  // overflow fallback (deg > DMAX): never in practice
    int s = csr_src[beg + d];
    float w = __expf(lrelu(a_s[s * 4 + h] + adh)) * invh;
    half4v r = *(const half4v*)(h1h + (size_t)s * 256 + lane * 4);
    acc.x = fmaf((float)r[0], w, acc.x); acc.y = fmaf((float)r[1], w, acc.y);
    acc.z = fmaf((float)r[2], w, acc.z); acc.w = fmaf((float)r[3], w, acc.w);
  }
  const int c = lane * 4;
  float4 bb = *(const float4*)(b1 + c);
  half4v o;
  o[0] = (_Float16)elu1(acc.x + bb.x);
  o[1] = (_Float16)elu1(acc.y + bb.y);
  o[2] = (_Float16)elu1(acc.z + bb.z);
  o[3] = (_Float16)elu1(acc.w + bb.w);
  __builtin_nontemporal_store(__builtin_bit_cast(unsigned long long, o),
                              (unsigned long long*)(h1e + (size_t)n * 256 + c));
}

// ---------------- fused attention layer 2 + final linear ----------------
__global__ __launch_bounds__(256) void k_attn2(const int* __restrict__ offs,
                                               const int* __restrict__ degarr,
                                               const int* __restrict__ csr_src,
                                               const float* __restrict__ a_s,
                                               const float* __restrict__ a_d,
                                               const _Float16* __restrict__ h2h,
                                               const float* __restrict__ b2,
                                               const float* __restrict__ lin_w,
                                               const float* __restrict__ lin_b,
                                               float* __restrict__ out) {
  __shared__ float alpha2[4][DMAX];
  __shared__ int sidx2[4][DMAX];
  const int wid = threadIdx.x >> 6;
  const int n = blockIdx.x * 4 + wid;
  const int lane = threadIdx.x & 63;
  const int beg = offs[n], deg = degarr[n];
  const float adn = a_d[n];
  float sm = 0.f;
  for (int d = lane; d < deg; d += 64) {
    int s = __builtin_nontemporal_load(csr_src + beg + d);
    float e = __expf(lrelu(a_s[s] + adn));
    sm += e;
    if (d < DMAX) { sidx2[wid][d] = s; alpha2[wid][d] = e; }
  }
  sm = wsum64(sm);
  const float inv = 1.f / sm;
  const int dlim = deg < DMAX ? deg : DMAX;
  for (int d = lane; d < dlim; d += 64) alpha2[wid][d] *= inv;
  float acc = 0.f;
  int d = 0;
  for (; d + 8 <= dlim; d += 8) {
    int ss[8]; float ww[8]; float vv[8];
#pragma unroll
    for (int u = 0; u < 8; ++u) {
      ss[u] = sidx2[wid][d + u];
      ww[u] = alpha2[wid][d + u];
    }
#pragma unroll
    for (int u = 0; u < 8; ++u)
      vv[u] = (float)h2h[(size_t)ss[u] * 64 + lane];
#pragma unroll
    for (int u = 0; u < 8; ++u) acc = fmaf(vv[u], ww[u], acc);
  }
  for (; d < dlim; ++d) {
    acc = fmaf((float)h2h[(size_t)sidx2[wid][d] * 64 + lane], alpha2[wid][d], acc);
  }
  for (; d < deg; ++d) {  // overflow fallback
    int s = csr_src[beg + d];
    float w = __expf(lrelu(a_s[s] + adn)) * inv;
    acc = fmaf((float)h2h[(size_t)s * 64 + lane], w, acc);
  }
  float o = elu1(acc + b2[lane]);
  float p0 = wsum64(o * lin_w[lane * 2 + 0]);
  float p1 = wsum64(o * lin_w[lane * 2 + 1]);
  if (lane == 0) {
    out[n * 2 + 0] = p0 + lin_b[0];
    out[n * 2 + 1] = p1 + lin_b[1];
  }
}

// ---------------- launch ----------------
extern "C" void kernel_launch(void* const* d_in, const int* in_sizes, int n_in,
                              void* d_out, int out_size, void* d_ws, size_t ws_size,
                              hipStream_t stream) {
  const float* x      = (const float*)d_in[0];
  const int*   ei     = (const int*)d_in[1];
  const float* W1     = (const float*)d_in[2];
  const float* a_src1 = (const float*)d_in[3];
  const float* a_dst1 = (const float*)d_in[4];
  const float* b1     = (const float*)d_in[5];
  const float* W2     = (const float*)d_in[6];
  const float* a_src2 = (const float*)d_in[7];
  const float* a_dst2 = (const float*)d_in[8];
  const float* b2     = (const float*)d_in[9];
  const float* lin_w  = (const float*)d_in[10];
  const float* lin_b  = (const float*)d_in[11];
  float* outp = (float*)d_out;

  char* w = (char*)d_ws;
  _Float16* h1h = (_Float16*)(w + 0);            // 51,200,000
  _Float16* h1e = (_Float16*)(w + 51200000);     // 51,200,000
  _Float16* h2h = (_Float16*)(w + 102400000);    // 12,800,000
  float*  as1 = (float*)(w + 115298304);         // 1,600,000
  float*  ad1 = (float*)(w + 116898304);         // 1,600,000
  float*  as2 = (float*)(w + 118498304);         // 400,000
  float*  ad2 = (float*)(w + 118898304);         // 400,000
  int*    offs = (int*)(w + 119298304);          // 400,000
  int*    degarr = (int*)(w + 119698304);        // 400,000
  int*    ccur = (int*)(w + 120098304);          // 1,024
  unsigned* ebuf = (unsigned*)(w + 120099328);   // 16,777,216
  int*    csr = (int*)(w + 136876544);           // 16,777,216

  // CSR build pass1 fused with gemm1 (independent work, one launch)
  hipMemsetAsync(ccur, 0, 1024, stream);
  k_fused1<<<NB0 + G1B, 256, 0, stream>>>(ei, ccur, ebuf, x, W1, a_src1, a_dst1,
                                          h1h, as1, ad1);
  k_pass2<<<256, 256, 0, stream>>>(ebuf, ccur, offs, degarr, csr);

  // layer 1 attention
  k_attn1<<<NN / 4, 256, 0, stream>>>(offs, degarr, csr, as1, ad1, h1h, b1, h1e);

  // layer 2
  k_gemm2m<<<1563, 256, 0, stream>>>(h1e, W2, a_src2, a_dst2, h2h, as2, ad2);
  k_attn2<<<NN / 4, 256, 0, stream>>>(offs, degarr, csr, as2, ad2, h2h, b2, lin_w, lin_b, outp);
}

// Round 9
// 615.517 us; speedup vs baseline: 2.4789x; 1.0362x over previous
//
#include <hip/hip_runtime.h>
#include <hip/hip_fp16.h>
#include <math.h>

#define NN 100000
#define EE 3200000
#define ETOT (EE + NN)
#define NEG_SLOPE 0.2f
#define DMAX 96
#define CHUNK 4096
#define NB0 ((ETOT + CHUNK - 1) / CHUNK)  // 806
#define RB 391                            // 256 * 391 >= NN
#define CAP 16384                         // window per coarse bucket

typedef _Float16 half8 __attribute__((ext_vector_type(8)));
typedef _Float16 half4v __attribute__((ext_vector_type(4)));
typedef float floatx4 __attribute__((ext_vector_type(4)));

// ---------------- helpers ----------------
__device__ __forceinline__ float wsum64(float v) {
#pragma unroll
  for (int o = 32; o; o >>= 1) v += __shfl_xor(v, o);
  return v;
}
__device__ __forceinline__ float lrelu(float v) { return v > 0.f ? v : NEG_SLOPE * v; }
__device__ __forceinline__ float elu1(float v) { return v > 0.f ? v : expm1f(v); }

// ---------------- init: window cursors ----------------
__global__ void k_init(int* __restrict__ ccur) {
  ccur[threadIdx.x] = threadIdx.x * CAP;
}

// ---------------- pass1: bucketize edges into fixed windows + weight prep ----------------
// payload: (dloc:9 | src:17). Small LDS -> high occupancy.
__global__ __launch_bounds__(256) void k_pass1(const int* __restrict__ ei,
                                               int* __restrict__ ccur,
                                               unsigned* __restrict__ ebuf,
                                               const float* __restrict__ W1,
                                               const float* __restrict__ W2,
                                               _Float16* __restrict__ W1t,
                                               _Float16* __restrict__ W2t) {
  int b = blockIdx.x;
  if (b >= NB0) {  // weight prep blocks (192 x 256 = 49152 = 32768 + 16384)
    int idx = (b - NB0) * 256 + threadIdx.x;
    if (idx < 32768) {
      int n = idx >> 7, k = idx & 127;
      W1t[idx] = (_Float16)W1[k * 256 + n];
    } else {
      int j = idx - 32768;
      int n = j >> 8, k = j & 255;
      W2t[j] = (_Float16)W2[k * 64 + n];
    }
    return;
  }
  __shared__ int h[256];
  __shared__ int cur[256];
  int t = threadIdx.x;
  h[t] = 0;
  __syncthreads();
  int base = b * CHUNK;
  int lim = base + CHUNK; if (lim > ETOT) lim = ETOT;
  for (int e = base + t; e < lim; e += 256) {
    int d = (e < EE) ? ei[EE + e] : (e - EE);
    atomicAdd(&h[(unsigned)d / (unsigned)RB], 1);
  }
  __syncthreads();
  if (h[t]) cur[t] = atomicAdd(&ccur[t], h[t]);
  __syncthreads();
  for (int e = base + t; e < lim; e += 256) {
    int s, d;
    if (e < EE) { s = ei[e]; d = ei[EE + e]; } else { s = e - EE; d = s; }
    unsigned cb = (unsigned)d / (unsigned)RB;
    unsigned dloc = (unsigned)d - cb * (unsigned)RB;
    int pos = atomicAdd(&cur[cb], 1);
    ebuf[pos] = (dloc << 17) | (unsigned)s;
  }
}

// ---------------- pass2: per-bucket exact placement via LDS cursors; emits offs+deg+csr ----
__global__ __launch_bounds__(256) void k_pass2(const unsigned* __restrict__ ebuf,
                                               const int* __restrict__ ccur,
                                               int* __restrict__ offs,
                                               int* __restrict__ degarr,
                                               int* __restrict__ csr) {
  __shared__ unsigned ed[CAP];
  __shared__ int hist[RB];
  __shared__ int cur[RB];
  int b = blockIdx.x, t = threadIdx.x;
  int d0 = b * RB;
  int rb = NN - d0; if (rb > RB) rb = RB;
  int w0 = b * CAP;
  int cnt = ccur[b] - w0;
  if (cnt > CAP) cnt = CAP;  // statistical impossibility guard
  for (int j = t; j < rb; j += 256) hist[j] = 0;
  __syncthreads();
  for (int i = t; i < cnt; i += 256) {
    unsigned v = ebuf[w0 + i];
    ed[i] = v;
    atomicAdd(&hist[v >> 17], 1);
  }
  __syncthreads();
  if (t == 0) {
    int run = w0;
    for (int j = 0; j < rb; ++j) { cur[j] = run; run += hist[j]; }
  }
  __syncthreads();
  for (int j = t; j < rb; j += 256) {
    offs[d0 + j] = cur[j];
    degarr[d0 + j] = hist[j];
  }
  __syncthreads();
  for (int i = t; i < cnt; i += 256) {
    unsigned v = ed[i];
    int pos = atomicAdd(&cur[v >> 17], 1);
    csr[pos] = (int)(v & 0x1FFFFu);
  }
}

// ---------------- GEMM1 (MFMA fp16): h1h + as1/ad1 from x@W1, 2 heads/block ----------------
__global__ __launch_bounds__(256) void k_gemm1m(const float* __restrict__ x,
                                                const _Float16* __restrict__ W1t,
                                                const float* __restrict__ a_src,
                                                const float* __restrict__ a_dst,
                                                _Float16* __restrict__ h1h,
                                                float* __restrict__ as_out,
                                                float* __restrict__ ad_out) {
  __shared__ _Float16 As[64][136];
  __shared__ _Float16 Wt[128][136];
  const int bx = blockIdx.x & 1;
  const int by = blockIdx.x >> 1;
  const int tid = threadIdx.x;
  const int row0 = by * 64;
#pragma unroll
  for (int i = 0; i < 8; ++i) {
    int idx = i * 256 + tid;
    int r = idx >> 5;
    int c4 = (idx & 31) * 4;
    int gr = row0 + r;
    float4 f = make_float4(0.f, 0.f, 0.f, 0.f);
    if (gr < NN) f = *(const float4*)(x + (size_t)gr * 128 + c4);
    half4v h; h[0] = (_Float16)f.x; h[1] = (_Float16)f.y; h[2] = (_Float16)f.z; h[3] = (_Float16)f.w;
    *(half4v*)&As[r][c4] = h;
  }
#pragma unroll
  for (int i = 0; i < 8; ++i) {
    int idx = i * 256 + tid;
    int r = idx >> 4;
    int g = idx & 15;
    *(half8*)&Wt[r][g * 8] = *(const half8*)(W1t + (size_t)(bx * 128 + r) * 128 + g * 8);
  }
  __syncthreads();

  const int wid = tid >> 6, lane = tid & 63;
  const int m16 = lane & 15, quad = lane >> 4;
  floatx4 acc[8];
#pragma unroll
  for (int nt = 0; nt < 8; ++nt) acc[nt] = (floatx4){0.f, 0.f, 0.f, 0.f};
#pragma unroll
  for (int ks = 0; ks < 4; ++ks) {
    half8 av = *(half8*)&As[wid * 16 + m16][ks * 32 + quad * 8];
#pragma unroll
    for (int nt = 0; nt < 8; ++nt) {
      half8 bv = *(half8*)&Wt[nt * 16 + m16][ks * 32 + quad * 8];
      acc[nt] = __builtin_amdgcn_mfma_f32_16x16x32_f16(av, bv, acc[nt], 0, 0, 0);
    }
  }
  float asr[8], adr[8];
#pragma unroll
  for (int nt = 0; nt < 8; ++nt) {
    asr[nt] = a_src[bx * 128 + nt * 16 + m16];
    adr[nt] = a_dst[bx * 128 + nt * 16 + m16];
  }
#pragma unroll
  for (int r = 0; r < 4; ++r) {
    int gr = row0 + wid * 16 + quad * 4 + r;
    bool ok = gr < NN;
#pragma unroll
    for (int hp = 0; hp < 2; ++hp) {
      float ps = 0.f, pd = 0.f;
#pragma unroll
      for (int j = 0; j < 4; ++j) {
        ps = fmaf(acc[hp * 4 + j][r], asr[hp * 4 + j], ps);
        pd = fmaf(acc[hp * 4 + j][r], adr[hp * 4 + j], pd);
      }
#pragma unroll
      for (int o = 1; o < 16; o <<= 1) { ps += __shfl_xor(ps, o); pd += __shfl_xor(pd, o); }
      if (ok && m16 == 0) {
        as_out[gr * 4 + bx * 2 + hp] = ps;
        ad_out[gr * 4 + bx * 2 + hp] = pd;
      }
    }
    if (ok) {
#pragma unroll
      for (int nt = 0; nt < 8; ++nt)
        h1h[(size_t)gr * 256 + bx * 128 + nt * 16 + m16] = (_Float16)acc[nt][r];
    }
  }
}

// ---------------- GEMM2 (MFMA fp16): h2h + as2/ad2 from h1e@W2 ----------------
__global__ __launch_bounds__(256) void k_gemm2m(const _Float16* __restrict__ h1e,
                                                const _Float16* __restrict__ W2t,
                                                const float* __restrict__ a_src,
                                                const float* __restrict__ a_dst,
                                                _Float16* __restrict__ h2h,
                                                float* __restrict__ as_out,
                                                float* __restrict__ ad_out) {
  __shared__ _Float16 As2[64][136];
  __shared__ _Float16 Wt2[64][264];
  const int by = blockIdx.x;
  const int tid = threadIdx.x;
  const int row0 = by * 64;
#pragma unroll
  for (int i = 0; i < 8; ++i) {
    int idx = i * 256 + tid;
    int r = idx >> 5;
    int g = idx & 31;
    *(half8*)&Wt2[r][g * 8] = *(const half8*)(W2t + (size_t)r * 256 + g * 8);
  }
  const int wid = tid >> 6, lane = tid & 63;
  const int m16 = lane & 15, quad = lane >> 4;
  floatx4 acc[4];
#pragma unroll
  for (int nt = 0; nt < 4; ++nt) acc[nt] = (floatx4){0.f, 0.f, 0.f, 0.f};

  for (int kc = 0; kc < 2; ++kc) {
#pragma unroll
    for (int i = 0; i < 4; ++i) {
      int idx = i * 256 + tid;
      int r = idx >> 4;
      int g = idx & 15;
      int gr = row0 + r;
      half8 v = {0, 0, 0, 0, 0, 0, 0, 0};
      if (gr < NN) v = *(const half8*)(h1e + (size_t)gr * 256 + kc * 128 + g * 8);
      *(half8*)&As2[r][g * 8] = v;
    }
    __syncthreads();
#pragma unroll
    for (int ks = 0; ks < 4; ++ks) {
      half8 av = *(half8*)&As2[wid * 16 + m16][ks * 32 + quad * 8];
#pragma unroll
      for (int nt = 0; nt < 4; ++nt) {
        half8 bv = *(half8*)&Wt2[nt * 16 + m16][kc * 128 + ks * 32 + quad * 8];
        acc[nt] = __builtin_amdgcn_mfma_f32_16x16x32_f16(av, bv, acc[nt], 0, 0, 0);
      }
    }
    __syncthreads();
  }
  float asr[4], adr[4];
#pragma unroll
  for (int nt = 0; nt < 4; ++nt) {
    asr[nt] = a_src[nt * 16 + m16];
    adr[nt] = a_dst[nt * 16 + m16];
  }
#pragma unroll
  for (int r = 0; r < 4; ++r) {
    float ps = 0.f, pd = 0.f;
#pragma unroll
    for (int nt = 0; nt < 4; ++nt) {
      ps = fmaf(acc[nt][r], asr[nt], ps);
      pd = fmaf(acc[nt][r], adr[nt], pd);
    }
#pragma unroll
    for (int o = 1; o < 16; o <<= 1) { ps += __shfl_xor(ps, o); pd += __shfl_xor(pd, o); }
    int gr = row0 + wid * 16 + quad * 4 + r;
    if (gr < NN) {
      if (m16 == 0) { as_out[gr] = ps; ad_out[gr] = pd; }
#pragma unroll
      for (int nt = 0; nt < 4; ++nt)
        h2h[(size_t)gr * 64 + nt * 16 + m16] = (_Float16)acc[nt][r];
    }
  }
}

// ---------------- fused attention layer 1 -> h1e (fp16) ----------------
// one wave per dst node; phase 2: full wave, 8 B/lane, 8-unroll (round-6 proven shape).
__global__ __launch_bounds__(256) void k_attn1(const int* __restrict__ offs,
                                               const int* __restrict__ degarr,
                                               const int* __restrict__ csr_src,
                                               const float* __restrict__ a_s,
                                               const float* __restrict__ a_d,
                                               const _Float16* __restrict__ h1h,
                                               const float* __restrict__ b1,
                                               _Float16* __restrict__ h1e) {
  __shared__ float alpha[4][DMAX][4];
  __shared__ int sidx[4][DMAX];
  const int wid = threadIdx.x >> 6;
  const int n = blockIdx.x * 4 + wid;
  const int lane = threadIdx.x & 63;
  const int beg = offs[n], deg = degarr[n];
  const float4 ad = *(const float4*)(a_d + n * 4);
  float4 sm = make_float4(0.f, 0.f, 0.f, 0.f);
  for (int d = lane; d < deg; d += 64) {
    int s = csr_src[beg + d];
    float4 as = *(const float4*)(a_s + s * 4);
    float e0 = __expf(lrelu(as.x + ad.x));
    float e1 = __expf(lrelu(as.y + ad.y));
    float e2 = __expf(lrelu(as.z + ad.z));
    float e3 = __expf(lrelu(as.w + ad.w));
    sm.x += e0; sm.y += e1; sm.z += e2; sm.w += e3;
    if (d < DMAX) {
      sidx[wid][d] = s;
      *(float4*)&alpha[wid][d][0] = make_float4(e0, e1, e2, e3);
    }
  }
  sm.x = wsum64(sm.x); sm.y = wsum64(sm.y); sm.z = wsum64(sm.z); sm.w = wsum64(sm.w);
  const float4 inv4 = make_float4(1.f / sm.x, 1.f / sm.y, 1.f / sm.z, 1.f / sm.w);
  const int dlim = deg < DMAX ? deg : DMAX;
  for (int d = lane; d < dlim; d += 64) {
    float4 a = *(float4*)&alpha[wid][d][0];
    a.x *= inv4.x; a.y *= inv4.y; a.z *= inv4.z; a.w *= inv4.w;
    *(float4*)&alpha[wid][d][0] = a;
  }
  const int h = lane >> 4;
  float4 acc = make_float4(0.f, 0.f, 0.f, 0.f);
  int d = 0;
  for (; d + 8 <= dlim; d += 8) {
    int ss[8]; float ww[8];
#pragma unroll
    for (int u = 0; u < 8; ++u) {
      ss[u] = sidx[wid][d + u];
      ww[u] = alpha[wid][d + u][h];
    }
    half4v rr[8];
#pragma unroll
    for (int u = 0; u < 8; ++u)
      rr[u] = *(const half4v*)(h1h + (size_t)ss[u] * 256 + lane * 4);
#pragma unroll
    for (int u = 0; u < 8; ++u) {
      acc.x = fmaf((float)rr[u][0], ww[u], acc.x);
      acc.y = fmaf((float)rr[u][1], ww[u], acc.y);
      acc.z = fmaf((float)rr[u][2], ww[u], acc.z);
      acc.w = fmaf((float)rr[u][3], ww[u], acc.w);
    }
  }
  for (; d < dlim; ++d) {
    int s = sidx[wid][d];
    float w = alpha[wid][d][h];
    half4v r = *(const half4v*)(h1h + (size_t)s * 256 + lane * 4);
    acc.x = fmaf((float)r[0], w, acc.x); acc.y = fmaf((float)r[1], w, acc.y);
    acc.z = fmaf((float)r[2], w, acc.z); acc.w = fmaf((float)r[3], w, acc.w);
  }
  const float adh = (h & 2) ? ((h & 1) ? ad.w : ad.z) : ((h & 1) ? ad.y : ad.x);
  const float invh = (h & 2) ? ((h & 1) ? inv4.w : inv4.z) : ((h & 1) ? inv4.y : inv4.x);
  for (; d < deg; ++d) {  // overflow fallback (deg > DMAX): never in practice
    int s = csr_src[beg + d];
    float w = __expf(lrelu(a_s[s * 4 + h] + adh)) * invh;
    half4v r = *(const half4v*)(h1h + (size_t)s * 256 + lane * 4);
    acc.x = fmaf((float)r[0], w, acc.x); acc.y = fmaf((float)r[1], w, acc.y);
    acc.z = fmaf((float)r[2], w, acc.z); acc.w = fmaf((float)r[3], w, acc.w);
  }
  const int c = lane * 4;
  float4 bb = *(const float4*)(b1 + c);
  half4v o;
  o[0] = (_Float16)elu1(acc.x + bb.x);
  o[1] = (_Float16)elu1(acc.y + bb.y);
  o[2] = (_Float16)elu1(acc.z + bb.z);
  o[3] = (_Float16)elu1(acc.w + bb.w);
  *(half4v*)(h1e + (size_t)n * 256 + c) = o;
}

// ---------------- fused attention layer 2 + final linear ----------------
// phase 2: quarter-wave per edge (16 lanes x 8 B = 128 B row), 2-unroll = 8 edges/iter.
__global__ __launch_bounds__(256) void k_attn2(const int* __restrict__ offs,
                                               const int* __restrict__ degarr,
                                               const int* __restrict__ csr_src,
                                               const float* __restrict__ a_s,
                                               const float* __restrict__ a_d,
                                               const _Float16* __restrict__ h2h,
                                               const float* __restrict__ b2,
                                               const float* __restrict__ lin_w,
                                               const float* __restrict__ lin_b,
                                               float* __restrict__ out) {
  __shared__ float alpha2[4][DMAX];
  __shared__ int sidx2[4][DMAX];
  const int wid = threadIdx.x >> 6;
  const int n = blockIdx.x * 4 + wid;
  const int lane = threadIdx.x & 63;
  const int beg = offs[n], deg = degarr[n];
  const float adn = a_d[n];
  float sm = 0.f;
  for (int d = lane; d < deg; d += 64) {
    int s = csr_src[beg + d];
    float e = __expf(lrelu(a_s[s] + adn));
    sm += e;
    if (d < DMAX) { sidx2[wid][d] = s; alpha2[wid][d] = e; }
  }
  sm = wsum64(sm);
  const float inv = 1.f / sm;
  const int dlim = deg < DMAX ? deg : DMAX;
  for (int d = lane; d < dlim; d += 64) alpha2[wid][d] *= inv;
  const int quarter = lane >> 4;
  const int fl = lane & 15;  // covers fp16 [fl*4, fl*4+4)
  float acc4[4];
#pragma unroll
  for (int i = 0; i < 4; ++i) acc4[i] = 0.f;
  for (int d = 0; d < dlim; d += 8) {
    int ss[2]; float ww[2];
#pragma unroll
    for (int u = 0; u < 2; ++u) {
      int e = d + 4 * u + quarter;
      bool valid = e < dlim;
      int e2 = valid ? e : 0;
      ss[u] = sidx2[wid][e2];
      ww[u] = valid ? alpha2[wid][e2] : 0.f;
    }
    half4v rr[2];
#pragma unroll
    for (int u = 0; u < 2; ++u)
      rr[u] = *(const half4v*)(h2h + (size_t)ss[u] * 64 + fl * 4);
#pragma unroll
    for (int u = 0; u < 2; ++u)
#pragma unroll
      for (int i = 0; i < 4; ++i)
        acc4[i] = fmaf((float)rr[u][i], ww[u], acc4[i]);
  }
  for (int d = dlim + quarter; d < deg; d += 4) {  // overflow fallback
    int s = csr_src[beg + d];
    float w = __expf(lrelu(a_s[s] + adn)) * inv;
    half4v r = *(const half4v*)(h2h + (size_t)s * 64 + fl * 4);
#pragma unroll
    for (int i = 0; i < 4; ++i) acc4[i] = fmaf((float)r[i], w, acc4[i]);
  }
#pragma unroll
  for (int i = 0; i < 4; ++i) {
    acc4[i] += __shfl_xor(acc4[i], 16);
    acc4[i] += __shfl_xor(acc4[i], 32);
  }
  float p0 = 0.f, p1 = 0.f;
#pragma unroll
  for (int i = 0; i < 4; ++i) {
    float o = elu1(acc4[i] + b2[fl * 4 + i]);
    p0 = fmaf(o, lin_w[(fl * 4 + i) * 2 + 0], p0);
    p1 = fmaf(o, lin_w[(fl * 4 + i) * 2 + 1], p1);
  }
#pragma unroll
  for (int o = 1; o < 16; o <<= 1) { p0 += __shfl_xor(p0, o); p1 += __shfl_xor(p1, o); }
  if (lane == 0) {
    out[n * 2 + 0] = p0 + lin_b[0];
    out[n * 2 + 1] = p1 + lin_b[1];
  }
}

// ---------------- launch ----------------
extern "C" void kernel_launch(void* const* d_in, const int* in_sizes, int n_in,
                              void* d_out, int out_size, void* d_ws, size_t ws_size,
                              hipStream_t stream) {
  const float* x      = (const float*)d_in[0];
  const int*   ei     = (const int*)d_in[1];
  const float* W1     = (const float*)d_in[2];
  const float* a_src1 = (const float*)d_in[3];
  const float* a_dst1 = (const float*)d_in[4];
  const float* b1     = (const float*)d_in[5];
  const float* W2     = (const float*)d_in[6];
  const float* a_src2 = (const float*)d_in[7];
  const float* a_dst2 = (const float*)d_in[8];
  const float* b2     = (const float*)d_in[9];
  const float* lin_w  = (const float*)d_in[10];
  const float* lin_b  = (const float*)d_in[11];
  float* outp = (float*)d_out;

  char* w = (char*)d_ws;
  _Float16* h1h = (_Float16*)(w + 0);            // 51,200,000
  _Float16* h1e = (_Float16*)(w + 51200000);     // 51,200,000
  _Float16* h2h = (_Float16*)(w + 102400000);    // 12,800,000
  _Float16* W1t = (_Float16*)(w + 115200000);    // 65,536
  _Float16* W2t = (_Float16*)(w + 115265536);    // 32,768
  float*  as1 = (float*)(w + 115298304);         // 1,600,000
  float*  ad1 = (float*)(w + 116898304);         // 1,600,000
  float*  as2 = (float*)(w + 118498304);         // 400,000
  float*  ad2 = (float*)(w + 118898304);         // 400,000
  int*    offs = (int*)(w + 119298304);          // 400,000
  int*    degarr = (int*)(w + 119698304);        // 400,000
  int*    ccur = (int*)(w + 120098304);          // 1,024
  unsigned* ebuf = (unsigned*)(w + 120099328);   // 16,777,216
  int*    csr = (int*)(w + 136876544);           // 16,777,216

  // CSR build (fixed-window counting sort) + weight prep
  k_init<<<1, 256, 0, stream>>>(ccur);
  k_pass1<<<NB0 + 192, 256, 0, stream>>>(ei, ccur, ebuf, W1, W2, W1t, W2t);
  k_pass2<<<256, 256, 0, stream>>>(ebuf, ccur, offs, degarr, csr);

  // layer 1
  k_gemm1m<<<2 * 1563, 256, 0, stream>>>(x, W1t, a_src1, a_dst1, h1h, as1, ad1);
  k_attn1<<<NN / 4, 256, 0, stream>>>(offs, degarr, csr, as1, ad1, h1h, b1, h1e);

  // layer 2
  k_gemm2m<<<1563, 256, 0, stream>>>(h1e, W2t, a_src2, a_dst2, h2h, as2, ad2);
  k_attn2<<<NN / 4, 256, 0, stream>>>(offs, degarr, csr, as2, ad2, h2h, b2, lin_w, lin_b, outp);
}

// Round 10
// 589.066 us; speedup vs baseline: 2.5902x; 1.0449x over previous
//
#include <hip/hip_runtime.h>
#include <hip/hip_fp16.h>
#include <math.h>

#define NN 100000
#define EE 3200000
#define ETOT (EE + NN)
#define NEG_SLOPE 0.2f
#define DMAX 96
#define CHUNK 4096
#define NB0 ((ETOT + CHUNK - 1) / CHUNK)  // 806
#define RB 391                            // 256 * 391 >= NN
#define CAP 16384                         // window per coarse bucket

typedef _Float16 half8 __attribute__((ext_vector_type(8)));
typedef _Float16 half4v __attribute__((ext_vector_type(4)));
typedef float floatx4 __attribute__((ext_vector_type(4)));

// ---------------- helpers ----------------
__device__ __forceinline__ float lrelu(float v) { return v > 0.f ? v : NEG_SLOPE * v; }
__device__ __forceinline__ float elu1(float v) { return v > 0.f ? v : expm1f(v); }

// ---------------- pass1: bucketize edges into fixed windows + weight prep ----------------
// ccur holds COUNTS (memset 0); window base = t*CAP. payload: (dloc:9 | src:17).
__global__ __launch_bounds__(256) void k_pass1(const int* __restrict__ ei,
                                               int* __restrict__ ccur,
                                               unsigned* __restrict__ ebuf,
                                               const float* __restrict__ W1,
                                               const float* __restrict__ W2,
                                               _Float16* __restrict__ W1t,
                                               _Float16* __restrict__ W2t) {
  int b = blockIdx.x;
  if (b >= NB0) {  // weight prep blocks (192 x 256 = 49152 = 32768 + 16384)
    int idx = (b - NB0) * 256 + threadIdx.x;
    if (idx < 32768) {
      int n = idx >> 7, k = idx & 127;
      W1t[idx] = (_Float16)W1[k * 256 + n];
    } else {
      int j = idx - 32768;
      int n = j >> 8, k = j & 255;
      W2t[j] = (_Float16)W2[k * 64 + n];
    }
    return;
  }
  __shared__ int h[256];
  __shared__ int cur[256];
  int t = threadIdx.x;
  h[t] = 0;
  __syncthreads();
  int base = b * CHUNK;
  int lim = base + CHUNK; if (lim > ETOT) lim = ETOT;
  for (int e = base + t; e < lim; e += 256) {
    int d = (e < EE) ? ei[EE + e] : (e - EE);
    atomicAdd(&h[(unsigned)d / (unsigned)RB], 1);
  }
  __syncthreads();
  if (h[t]) cur[t] = t * CAP + atomicAdd(&ccur[t], h[t]);
  __syncthreads();
  for (int e = base + t; e < lim; e += 256) {
    int s, d;
    if (e < EE) { s = ei[e]; d = ei[EE + e]; } else { s = e - EE; d = s; }
    unsigned cb = (unsigned)d / (unsigned)RB;
    unsigned dloc = (unsigned)d - cb * (unsigned)RB;
    int pos = atomicAdd(&cur[cb], 1);
    ebuf[pos] = (dloc << 17) | (unsigned)s;
  }
}

// ---------------- pass2: per-bucket exact placement via LDS cursors; emits offs+deg+csr ----
__global__ __launch_bounds__(256) void k_pass2(const unsigned* __restrict__ ebuf,
                                               const int* __restrict__ ccur,
                                               int* __restrict__ offs,
                                               int* __restrict__ degarr,
                                               int* __restrict__ csr) {
  __shared__ unsigned ed[CAP];
  __shared__ int hist[RB];
  __shared__ int cur[RB];
  int b = blockIdx.x, t = threadIdx.x;
  int d0 = b * RB;
  int rb = NN - d0; if (rb > RB) rb = RB;
  int w0 = b * CAP;
  int cnt = ccur[b];
  if (cnt > CAP) cnt = CAP;  // statistical impossibility guard
  for (int j = t; j < rb; j += 256) hist[j] = 0;
  __syncthreads();
  for (int i = t; i < cnt; i += 256) {
    unsigned v = ebuf[w0 + i];
    ed[i] = v;
    atomicAdd(&hist[v >> 17], 1);
  }
  __syncthreads();
  if (t == 0) {
    int run = w0;
    for (int j = 0; j < rb; ++j) { cur[j] = run; run += hist[j]; }
  }
  __syncthreads();
  for (int j = t; j < rb; j += 256) {
    offs[d0 + j] = cur[j];
    degarr[d0 + j] = hist[j];
  }
  __syncthreads();
  for (int i = t; i < cnt; i += 256) {
    unsigned v = ed[i];
    int pos = atomicAdd(&cur[v >> 17], 1);
    csr[pos] = (int)(v & 0x1FFFFu);
  }
}

// ---------------- GEMM1 (MFMA fp16): h1h + as1/ad1 from x@W1, 2 heads/block ----------------
__global__ __launch_bounds__(256) void k_gemm1m(const float* __restrict__ x,
                                                const _Float16* __restrict__ W1t,
                                                const float* __restrict__ a_src,
                                                const float* __restrict__ a_dst,
                                                _Float16* __restrict__ h1h,
                                                float* __restrict__ as_out,
                                                float* __restrict__ ad_out) {
  __shared__ _Float16 As[64][136];
  __shared__ _Float16 Wt[128][136];
  const int bx = blockIdx.x & 1;
  const int by = blockIdx.x >> 1;
  const int tid = threadIdx.x;
  const int row0 = by * 64;
#pragma unroll
  for (int i = 0; i < 8; ++i) {
    int idx = i * 256 + tid;
    int r = idx >> 5;
    int c4 = (idx & 31) * 4;
    int gr = row0 + r;
    float4 f = make_float4(0.f, 0.f, 0.f, 0.f);
    if (gr < NN) f = *(const float4*)(x + (size_t)gr * 128 + c4);
    half4v h; h[0] = (_Float16)f.x; h[1] = (_Float16)f.y; h[2] = (_Float16)f.z; h[3] = (_Float16)f.w;
    *(half4v*)&As[r][c4] = h;
  }
#pragma unroll
  for (int i = 0; i < 8; ++i) {
    int idx = i * 256 + tid;
    int r = idx >> 4;
    int g = idx & 15;
    *(half8*)&Wt[r][g * 8] = *(const half8*)(W1t + (size_t)(bx * 128 + r) * 128 + g * 8);
  }
  __syncthreads();

  const int wid = tid >> 6, lane = tid & 63;
  const int m16 = lane & 15, quad = lane >> 4;
  floatx4 acc[8];
#pragma unroll
  for (int nt = 0; nt < 8; ++nt) acc[nt] = (floatx4){0.f, 0.f, 0.f, 0.f};
#pragma unroll
  for (int ks = 0; ks < 4; ++ks) {
    half8 av = *(half8*)&As[wid * 16 + m16][ks * 32 + quad * 8];
#pragma unroll
    for (int nt = 0; nt < 8; ++nt) {
      half8 bv = *(half8*)&Wt[nt * 16 + m16][ks * 32 + quad * 8];
      acc[nt] = __builtin_amdgcn_mfma_f32_16x16x32_f16(av, bv, acc[nt], 0, 0, 0);
    }
  }
  float asr[8], adr[8];
#pragma unroll
  for (int nt = 0; nt < 8; ++nt) {
    asr[nt] = a_src[bx * 128 + nt * 16 + m16];
    adr[nt] = a_dst[bx * 128 + nt * 16 + m16];
  }
#pragma unroll
  for (int r = 0; r < 4; ++r) {
    int gr = row0 + wid * 16 + quad * 4 + r;
    bool ok = gr < NN;
#pragma unroll
    for (int hp = 0; hp < 2; ++hp) {
      float ps = 0.f, pd = 0.f;
#pragma unroll
      for (int j = 0; j < 4; ++j) {
        ps = fmaf(acc[hp * 4 + j][r], asr[hp * 4 + j], ps);
        pd = fmaf(acc[hp * 4 + j][r], adr[hp * 4 + j], pd);
      }
#pragma unroll
      for (int o = 1; o < 16; o <<= 1) { ps += __shfl_xor(ps, o); pd += __shfl_xor(pd, o); }
      if (ok && m16 == 0) {
        as_out[gr * 4 + bx * 2 + hp] = ps;
        ad_out[gr * 4 + bx * 2 + hp] = pd;
      }
    }
    if (ok) {
#pragma unroll
      for (int nt = 0; nt < 8; ++nt)
        h1h[(size_t)gr * 256 + bx * 128 + nt * 16 + m16] = (_Float16)acc[nt][r];
    }
  }
}

// ---------------- GEMM2 (MFMA fp16): h2h + as2/ad2 from h1e@W2 ----------------
__global__ __launch_bounds__(256) void k_gemm2m(const _Float16* __restrict__ h1e,
                                                const _Float16* __restrict__ W2t,
                                                const float* __restrict__ a_src,
                                                const float* __restrict__ a_dst,
                                                _Float16* __restrict__ h2h,
                                                float* __restrict__ as_out,
                                                float* __restrict__ ad_out) {
  __shared__ _Float16 As2[64][136];
  __shared__ _Float16 Wt2[64][264];
  const int by = blockIdx.x;
  const int tid = threadIdx.x;
  const int row0 = by * 64;
#pragma unroll
  for (int i = 0; i < 8; ++i) {
    int idx = i * 256 + tid;
    int r = idx >> 5;
    int g = idx & 31;
    *(half8*)&Wt2[r][g * 8] = *(const half8*)(W2t + (size_t)r * 256 + g * 8);
  }
  const int wid = tid >> 6, lane = tid & 63;
  const int m16 = lane & 15, quad = lane >> 4;
  floatx4 acc[4];
#pragma unroll
  for (int nt = 0; nt < 4; ++nt) acc[nt] = (floatx4){0.f, 0.f, 0.f, 0.f};

  for (int kc = 0; kc < 2; ++kc) {
#pragma unroll
    for (int i = 0; i < 4; ++i) {
      int idx = i * 256 + tid;
      int r = idx >> 4;
      int g = idx & 15;
      int gr = row0 + r;
      half8 v = {0, 0, 0, 0, 0, 0, 0, 0};
      if (gr < NN) v = *(const half8*)(h1e + (size_t)gr * 256 + kc * 128 + g * 8);
      *(half8*)&As2[r][g * 8] = v;
    }
    __syncthreads();
#pragma unroll
    for (int ks = 0; ks < 4; ++ks) {
      half8 av = *(half8*)&As2[wid * 16 + m16][ks * 32 + quad * 8];
#pragma unroll
      for (int nt = 0; nt < 4; ++nt) {
        half8 bv = *(half8*)&Wt2[nt * 16 + m16][kc * 128 + ks * 32 + quad * 8];
        acc[nt] = __builtin_amdgcn_mfma_f32_16x16x32_f16(av, bv, acc[nt], 0, 0, 0);
      }
    }
    __syncthreads();
  }
  float asr[4], adr[4];
#pragma unroll
  for (int nt = 0; nt < 4; ++nt) {
    asr[nt] = a_src[nt * 16 + m16];
    adr[nt] = a_dst[nt * 16 + m16];
  }
#pragma unroll
  for (int r = 0; r < 4; ++r) {
    float ps = 0.f, pd = 0.f;
#pragma unroll
    for (int nt = 0; nt < 4; ++nt) {
      ps = fmaf(acc[nt][r], asr[nt], ps);
      pd = fmaf(acc[nt][r], adr[nt], pd);
    }
#pragma unroll
    for (int o = 1; o < 16; o <<= 1) { ps += __shfl_xor(ps, o); pd += __shfl_xor(pd, o); }
    int gr = row0 + wid * 16 + quad * 4 + r;
    if (gr < NN) {
      if (m16 == 0) { as_out[gr] = ps; ad_out[gr] = pd; }
#pragma unroll
      for (int nt = 0; nt < 4; ++nt)
        h2h[(size_t)gr * 64 + nt * 16 + m16] = (_Float16)acc[nt][r];
    }
  }
}

// ---------------- attn1: 32-lane group owns one dst; 16 B/lane row loads ----------------
__global__ __launch_bounds__(256) void k_attn1(const int* __restrict__ offs,
                                               const int* __restrict__ degarr,
                                               const int* __restrict__ csr_src,
                                               const float* __restrict__ a_s,
                                               const float* __restrict__ a_d,
                                               const _Float16* __restrict__ h1h,
                                               const float* __restrict__ b1,
                                               _Float16* __restrict__ h1e) {
  __shared__ float alpha[8][DMAX][4];
  __shared__ int sidx[8][DMAX];
  const int g = threadIdx.x >> 5;       // dst group 0..7
  const int gl = threadIdx.x & 31;      // lane in group
  const int n = blockIdx.x * 8 + g;
  const int beg = offs[n], deg = degarr[n];
  const float4 ad = *(const float4*)(a_d + (size_t)n * 4);
  float4 sm = make_float4(0.f, 0.f, 0.f, 0.f);
  for (int d = gl; d < deg; d += 32) {
    int s = csr_src[beg + d];
    float4 as = *(const float4*)(a_s + (size_t)s * 4);
    float e0 = __expf(lrelu(as.x + ad.x));
    float e1 = __expf(lrelu(as.y + ad.y));
    float e2 = __expf(lrelu(as.z + ad.z));
    float e3 = __expf(lrelu(as.w + ad.w));
    sm.x += e0; sm.y += e1; sm.z += e2; sm.w += e3;
    if (d < DMAX) {
      sidx[g][d] = s;
      *(float4*)&alpha[g][d][0] = make_float4(e0, e1, e2, e3);
    }
  }
#pragma unroll
  for (int o = 16; o; o >>= 1) {
    sm.x += __shfl_xor(sm.x, o); sm.y += __shfl_xor(sm.y, o);
    sm.z += __shfl_xor(sm.z, o); sm.w += __shfl_xor(sm.w, o);
  }
  const float4 inv4 = make_float4(1.f / sm.x, 1.f / sm.y, 1.f / sm.z, 1.f / sm.w);
  const int dlim = deg < DMAX ? deg : DMAX;
  for (int d = gl; d < dlim; d += 32) {
    float4 a = *(float4*)&alpha[g][d][0];
    a.x *= inv4.x; a.y *= inv4.y; a.z *= inv4.z; a.w *= inv4.w;
    *(float4*)&alpha[g][d][0] = a;
  }
  const int h = gl >> 3;                // head for feats [gl*8, gl*8+8)
  float acc8[8];
#pragma unroll
  for (int i = 0; i < 8; ++i) acc8[i] = 0.f;
  int d = 0;
  for (; d + 8 <= dlim; d += 8) {
    int ss[8]; float ww[8];
#pragma unroll
    for (int u = 0; u < 8; ++u) {
      ss[u] = sidx[g][d + u];
      ww[u] = alpha[g][d + u][h];
    }
    half8 rr[8];
#pragma unroll
    for (int u = 0; u < 8; ++u)
      rr[u] = *(const half8*)(h1h + (size_t)ss[u] * 256 + gl * 8);
#pragma unroll
    for (int u = 0; u < 8; ++u)
#pragma unroll
      for (int i = 0; i < 8; ++i)
        acc8[i] = fmaf((float)rr[u][i], ww[u], acc8[i]);
  }
  for (; d < dlim; ++d) {
    int s = sidx[g][d];
    float w = alpha[g][d][h];
    half8 r = *(const half8*)(h1h + (size_t)s * 256 + gl * 8);
#pragma unroll
    for (int i = 0; i < 8; ++i) acc8[i] = fmaf((float)r[i], w, acc8[i]);
  }
  const float adh = (h & 2) ? ((h & 1) ? ad.w : ad.z) : ((h & 1) ? ad.y : ad.x);
  const float invh = (h & 2) ? ((h & 1) ? inv4.w : inv4.z) : ((h & 1) ? inv4.y : inv4.x);
  for (; d < deg; ++d) {  // overflow fallback (deg > DMAX): never in practice
    int s = csr_src[beg + d];
    float w = __expf(lrelu(a_s[(size_t)s * 4 + h] + adh)) * invh;
    half8 r = *(const half8*)(h1h + (size_t)s * 256 + gl * 8);
#pragma unroll
    for (int i = 0; i < 8; ++i) acc8[i] = fmaf((float)r[i], w, acc8[i]);
  }
  const int c = gl * 8;
  float4 bb0 = *(const float4*)(b1 + c);
  float4 bb1 = *(const float4*)(b1 + c + 4);
  half8 o;
  o[0] = (_Float16)elu1(acc8[0] + bb0.x);
  o[1] = (_Float16)elu1(acc8[1] + bb0.y);
  o[2] = (_Float16)elu1(acc8[2] + bb0.z);
  o[3] = (_Float16)elu1(acc8[3] + bb0.w);
  o[4] = (_Float16)elu1(acc8[4] + bb1.x);
  o[5] = (_Float16)elu1(acc8[5] + bb1.y);
  o[6] = (_Float16)elu1(acc8[6] + bb1.z);
  o[7] = (_Float16)elu1(acc8[7] + bb1.w);
  *(half8*)(h1e + (size_t)n * 256 + c) = o;
}

// ---------------- attn2: 16-lane group owns one dst; 8 B/lane row loads + final linear ----
__global__ __launch_bounds__(256) void k_attn2(const int* __restrict__ offs,
                                               const int* __restrict__ degarr,
                                               const int* __restrict__ csr_src,
                                               const float* __restrict__ a_s,
                                               const float* __restrict__ a_d,
                                               const _Float16* __restrict__ h2h,
                                               const float* __restrict__ b2,
                                               const float* __restrict__ lin_w,
                                               const float* __restrict__ lin_b,
                                               float* __restrict__ out) {
  __shared__ float alpha2[16][DMAX];
  __shared__ int sidx2[16][DMAX];
  const int g = threadIdx.x >> 4;       // dst group 0..15
  const int gl = threadIdx.x & 15;
  const int n = blockIdx.x * 16 + g;
  const int beg = offs[n], deg = degarr[n];
  const float adn = a_d[n];
  float sm = 0.f;
  for (int d = gl; d < deg; d += 16) {
    int s = csr_src[beg + d];
    float e = __expf(lrelu(a_s[s] + adn));
    sm += e;
    if (d < DMAX) { sidx2[g][d] = s; alpha2[g][d] = e; }
  }
#pragma unroll
  for (int o = 8; o; o >>= 1) sm += __shfl_xor(sm, o);
  const float inv = 1.f / sm;
  const int dlim = deg < DMAX ? deg : DMAX;
  for (int d = gl; d < dlim; d += 16) alpha2[g][d] *= inv;
  float acc4[4];
#pragma unroll
  for (int i = 0; i < 4; ++i) acc4[i] = 0.f;
  int d = 0;
  for (; d + 8 <= dlim; d += 8) {
    int ss[8]; float ww[8];
#pragma unroll
    for (int u = 0; u < 8; ++u) {
      ss[u] = sidx2[g][d + u];
      ww[u] = alpha2[g][d + u];
    }
    half4v rr[8];
#pragma unroll
    for (int u = 0; u < 8; ++u)
      rr[u] = *(const half4v*)(h2h + (size_t)ss[u] * 64 + gl * 4);
#pragma unroll
    for (int u = 0; u < 8; ++u)
#pragma unroll
      for (int i = 0; i < 4; ++i)
        acc4[i] = fmaf((float)rr[u][i], ww[u], acc4[i]);
  }
  for (; d < dlim; ++d) {
    int s = sidx2[g][d];
    float w = alpha2[g][d];
    half4v r = *(const half4v*)(h2h + (size_t)s * 64 + gl * 4);
#pragma unroll
    for (int i = 0; i < 4; ++i) acc4[i] = fmaf((float)r[i], w, acc4[i]);
  }
  for (; d < deg; ++d) {  // overflow fallback
    int s = csr_src[beg + d];
    float w = __expf(lrelu(a_s[s] + adn)) * inv;
    half4v r = *(const half4v*)(h2h + (size_t)s * 64 + gl * 4);
#pragma unroll
    for (int i = 0; i < 4; ++i) acc4[i] = fmaf((float)r[i], w, acc4[i]);
  }
  float p0 = 0.f, p1 = 0.f;
#pragma unroll
  for (int i = 0; i < 4; ++i) {
    float o = elu1(acc4[i] + b2[gl * 4 + i]);
    p0 = fmaf(o, lin_w[(gl * 4 + i) * 2 + 0], p0);
    p1 = fmaf(o, lin_w[(gl * 4 + i) * 2 + 1], p1);
  }
#pragma unroll
  for (int o = 8; o; o >>= 1) { p0 += __shfl_xor(p0, o); p1 += __shfl_xor(p1, o); }
  if (gl == 0) {
    out[n * 2 + 0] = p0 + lin_b[0];
    out[n * 2 + 1] = p1 + lin_b[1];
  }
}

// ---------------- launch ----------------
extern "C" void kernel_launch(void* const* d_in, const int* in_sizes, int n_in,
                              void* d_out, int out_size, void* d_ws, size_t ws_size,
                              hipStream_t stream) {
  const float* x      = (const float*)d_in[0];
  const int*   ei     = (const int*)d_in[1];
  const float* W1     = (const float*)d_in[2];
  const float* a_src1 = (const float*)d_in[3];
  const float* a_dst1 = (const float*)d_in[4];
  const float* b1     = (const float*)d_in[5];
  const float* W2     = (const float*)d_in[6];
  const float* a_src2 = (const float*)d_in[7];
  const float* a_dst2 = (const float*)d_in[8];
  const float* b2     = (const float*)d_in[9];
  const float* lin_w  = (const float*)d_in[10];
  const float* lin_b  = (const float*)d_in[11];
  float* outp = (float*)d_out;

  char* w = (char*)d_ws;
  _Float16* h1h = (_Float16*)(w + 0);            // 51,200,000
  _Float16* h1e = (_Float16*)(w + 51200000);     // 51,200,000
  _Float16* h2h = (_Float16*)(w + 102400000);    // 12,800,000
  _Float16* W1t = (_Float16*)(w + 115200000);    // 65,536
  _Float16* W2t = (_Float16*)(w + 115265536);    // 32,768
  float*  as1 = (float*)(w + 115298304);         // 1,600,000
  float*  ad1 = (float*)(w + 116898304);         // 1,600,000
  float*  as2 = (float*)(w + 118498304);         // 400,000
  float*  ad2 = (float*)(w + 118898304);         // 400,000
  int*    offs = (int*)(w + 119298304);          // 400,000
  int*    degarr = (int*)(w + 119698304);        // 400,000
  int*    ccur = (int*)(w + 120098304);          // 1,024
  unsigned* ebuf = (unsigned*)(w + 120099328);   // 16,777,216
  int*    csr = (int*)(w + 136876544);           // 16,777,216

  // CSR build (fixed-window counting sort) + weight prep
  hipMemsetAsync(ccur, 0, 1024, stream);
  k_pass1<<<NB0 + 192, 256, 0, stream>>>(ei, ccur, ebuf, W1, W2, W1t, W2t);
  k_pass2<<<256, 256, 0, stream>>>(ebuf, ccur, offs, degarr, csr);

  // layer 1
  k_gemm1m<<<2 * 1563, 256, 0, stream>>>(x, W1t, a_src1, a_dst1, h1h, as1, ad1);
  k_attn1<<<NN / 8, 256, 0, stream>>>(offs, degarr, csr, as1, ad1, h1h, b1, h1e);

  // layer 2
  k_gemm2m<<<1563, 256, 0, stream>>>(h1e, W2t, a_src2, a_dst2, h2h, as2, ad2);
  k_attn2<<<NN / 16, 256, 0, stream>>>(offs, degarr, csr, as2, ad2, h2h, b2, lin_w, lin_b, outp);
}